// Round 2
// baseline (270.128 us; speedup 1.0000x reference)
//
#include <hip/hip_runtime.h>
#include <hip/hip_bf16.h>
#include <stdint.h>

// Problem constants (from reference)
#define B_N     2048
#define E_N     32
#define IN_N    2048
#define OUT_N   1024
#define TOPK    4

// GEMM tiling
#define BM      64
#define BN      128
#define BK      64
#define NT      (OUT_N / BN)        // 8 n-tiles
#define NKT     (IN_N / BK)         // 32 k-steps
#define THREADS 256                 // 4 waves
#define MAX_SLOTS 160               // sum ceil(count_e/BM) <= 8192/64 + 32
#define GRID_GEMM (MAX_SLOTS * NT)  // 1280, divisible by 8 (XCD swizzle bijective)

// ws layout (int words)
#define WS_COUNTS 0     // [32]
#define WS_NSLOTS 32    // [1]
#define WS_DESC   64    // [MAX_SLOTS]  packed (e<<6)|mt
#define WS_LISTS  256   // [E_N][B_N]   packed (b<<2)|k

typedef float  f32x4  __attribute__((ext_vector_type(4)));
typedef __bf16 bf16x8 __attribute__((ext_vector_type(8)));

union Pack8 { bf16x8 v; uint4 u; };

__device__ __forceinline__ uint4 pack8(f32x4 lo, f32x4 hi) {
  Pack8 p;
#pragma unroll
  for (int j = 0; j < 4; ++j) { p.v[j] = (__bf16)lo[j]; p.v[j + 4] = (__bf16)hi[j]; }
  return p.u;
}
__device__ __forceinline__ bf16x8 as_frag(uint4 u) { Pack8 p; p.u = u; return p.v; }

// ---------------- kernel 0: zero counters ----------------
__global__ void k_zero(int* __restrict__ ws) {
  if (threadIdx.x < 64) ws[threadIdx.x] = 0;
}

// ---------------- kernel 1: top-4-smallest + bucket ----------------
__global__ void k_topk(const float* __restrict__ act, int* __restrict__ ws) {
  int b = blockIdx.x * blockDim.x + threadIdx.x;
  if (b >= B_N) return;
  float v[E_N];
  const float* a = act + (size_t)b * E_N;
#pragma unroll
  for (int e = 0; e < E_N; ++e) v[e] = a[e];
  unsigned chosen = 0;
#pragma unroll
  for (int k = 0; k < TOPK; ++k) {
    float mv = 3.4e38f; int mi = 0;
#pragma unroll
    for (int e = 0; e < E_N; ++e) {
      bool sel = (((chosen >> e) & 1u) == 0u) && (v[e] < mv);  // strict <: stable (first index)
      mv = sel ? v[e] : mv;
      mi = sel ? e : mi;
    }
    chosen |= (1u << mi);
    int pos = atomicAdd(&ws[WS_COUNTS + mi], 1);
    ws[WS_LISTS + mi * B_N + pos] = (b << 2) | k;
  }
}

// ---------------- kernel 2: build tile worklist ----------------
__global__ void k_tiles(int* __restrict__ ws) {
  int e = threadIdx.x;  // launched with 64 (one wave)
  int c = (e < E_N) ? ws[WS_COUNTS + e] : 0;
  int t = (c + BM - 1) / BM;
  int off = 0, tot = 0;
  for (int j = 0; j < E_N; ++j) {
    int tj = __shfl(t, j, 64);
    if (j < e) off += tj;
    tot += tj;
  }
  if (e < E_N) {
    for (int i = 0; i < t; ++i) ws[WS_DESC + off + i] = (e << 6) | i;
  }
  if (e == 0) ws[WS_NSLOTS] = tot;
}

// ---------------- kernel 3: grouped GEMM (bf16 MFMA) ----------------
// 64x128 block tile, BK=64, reg-staged prefetch + LDS double-buffer,
// 1 barrier per K-step. 4 waves; wave wv owns cols [wv*32, wv*32+32).
__global__ __launch_bounds__(THREADS, 3)
void k_gemm(const float* __restrict__ feat, const float* __restrict__ Wm,
            const float* __restrict__ bias, const int* __restrict__ ws,
            float* __restrict__ out) {
  // XCD-chunked swizzle (bijective: GRID_GEMM % 8 == 0)
  int p = blockIdx.x;
  int L = (p & 7) * (GRID_GEMM / 8) + (p >> 3);
  int slot = L >> 3;       // logical order: slot-major, nt inner
  int nt   = L & 7;
  if (slot >= ws[WS_NSLOTS]) return;
  int desc = ws[WS_DESC + slot];
  int e = desc >> 6, mt = desc & 63;
  int count = ws[WS_COUNTS + e];
  int m0 = mt * BM;

  // LDS: [A buf0 512][A buf1 512][W buf0 1024][W buf1 1024] uint4 slots = 48KB
  __shared__ uint4 lds4[3072];
  __shared__ int gids[BM];

  int tid  = threadIdx.x;
  int lane = tid & 63;
  int wv   = tid >> 6;

  // --- A staging: 4 threads/row, 16 floats each (64B) ---
  int arow = tid >> 2, kq = tid & 3;
  int gid = -1;
  if (m0 + arow < count) gid = ws[WS_LISTS + e * B_N + m0 + arow];
  if (kq == 0) gids[arow] = gid;
  const float* aptr = feat + (size_t)(gid >> 2) * IN_N + kq * 16;  // only deref'd if gid>=0
  int a_wi0 = arow * 8 + ((kq * 2)     ^ (arow & 7));
  int a_wi1 = arow * 8 + ((kq * 2 + 1) ^ (arow & 7));

  // --- W staging: 2 threads/row, 32 floats each (128B) ---
  int wrow = tid >> 1, kh = tid & 1;
  const float* wptr = Wm + ((size_t)e * OUT_N + (size_t)(nt * BN + wrow)) * IN_N + kh * 32;
  int w_wi[4];
#pragma unroll
  for (int s = 0; s < 4; ++s) w_wi[s] = wrow * 8 + ((kh * 4 + s) ^ (wrow & 7));

  // --- fragment read indices (uint4 units, swizzled) ---
  int aidx[4][2], bidx[2][2];
#pragma unroll
  for (int mi = 0; mi < 4; ++mi) {
    int r = mi * 16 + (lane & 15);
#pragma unroll
    for (int ks = 0; ks < 2; ++ks)
      aidx[mi][ks] = r * 8 + ((ks * 4 + (lane >> 4)) ^ (r & 7));
  }
#pragma unroll
  for (int ni = 0; ni < 2; ++ni) {
    int r = wv * 32 + ni * 16 + (lane & 15);
#pragma unroll
    for (int ks = 0; ks < 2; ++ks)
      bidx[ni][ks] = r * 8 + ((ks * 4 + (lane >> 4)) ^ (r & 7));
  }

  f32x4 ra[4], rw[8];
  const f32x4 zero4 = {0.f, 0.f, 0.f, 0.f};

#define LOAD_TILE(K0)                                                  \
  do {                                                                 \
    if (gid >= 0) {                                                    \
      _Pragma("unroll")                                                \
      for (int i = 0; i < 4; ++i) ra[i] = *(const f32x4*)(aptr + (K0) + i * 4); \
    } else {                                                           \
      _Pragma("unroll")                                                \
      for (int i = 0; i < 4; ++i) ra[i] = zero4;                       \
    }                                                                  \
    _Pragma("unroll")                                                  \
    for (int i = 0; i < 8; ++i) rw[i] = *(const f32x4*)(wptr + (K0) + i * 4); \
  } while (0)

#define WRITE_TILE(BUF)                                                \
  do {                                                                 \
    lds4[(BUF) * 512 + a_wi0] = pack8(ra[0], ra[1]);                   \
    lds4[(BUF) * 512 + a_wi1] = pack8(ra[2], ra[3]);                   \
    _Pragma("unroll")                                                  \
    for (int s = 0; s < 4; ++s)                                        \
      lds4[1024 + (BUF) * 1024 + w_wi[s]] = pack8(rw[2 * s], rw[2 * s + 1]); \
  } while (0)

  f32x4 acc[4][2] = {};  // [mi][ni]

  LOAD_TILE(0);
  WRITE_TILE(0);
  __syncthreads();

  int cur = 0;
#pragma unroll 1
  for (int kt = 0; kt < NKT; ++kt) {
    bool pf = (kt + 1 < NKT);
    if (pf) LOAD_TILE((kt + 1) * BK);   // issue next tile's loads before compute

    int ab = cur * 512;
    int wb = 1024 + cur * 1024;
#pragma unroll
    for (int ks = 0; ks < 2; ++ks) {
      bf16x8 af[4], bfr[2];
#pragma unroll
      for (int mi = 0; mi < 4; ++mi) af[mi] = as_frag(lds4[ab + aidx[mi][ks]]);
#pragma unroll
      for (int ni = 0; ni < 2; ++ni) bfr[ni] = as_frag(lds4[wb + bidx[ni][ks]]);
#pragma unroll
      for (int mi = 0; mi < 4; ++mi)
#pragma unroll
        for (int ni = 0; ni < 2; ++ni)
          acc[mi][ni] = __builtin_amdgcn_mfma_f32_16x16x32_bf16(af[mi], bfr[ni], acc[mi][ni], 0, 0, 0);
    }

    if (pf) WRITE_TILE(cur ^ 1);        // other buffer: no barrier needed before write
    __syncthreads();                    // joint: writes landed + everyone done reading cur
    cur ^= 1;
  }

  // --- epilogue: D row=(lane>>4)*4+j, col=lane&15 ---
  int grr[16];
#pragma unroll
  for (int mi = 0; mi < 4; ++mi)
#pragma unroll
    for (int j = 0; j < 4; ++j) grr[mi * 4 + j] = gids[mi * 16 + (lane >> 4) * 4 + j];

#pragma unroll
  for (int ni = 0; ni < 2; ++ni) {
    int col = nt * BN + wv * 32 + ni * 16 + (lane & 15);
    float bs = bias[e * OUT_N + col];
#pragma unroll
    for (int mi = 0; mi < 4; ++mi) {
#pragma unroll
      for (int j = 0; j < 4; ++j) {
        int g = grr[mi * 4 + j];
        if (g >= 0) out[(size_t)g * OUT_N + col] = acc[mi][ni][j] + bs;
      }
    }
  }
}

extern "C" void kernel_launch(void* const* d_in, const int* in_sizes, int n_in,
                              void* d_out, int out_size, void* d_ws, size_t ws_size,
                              hipStream_t stream) {
  const float* feat = (const float*)d_in[0];   // [B, IN]
  const float* Wm   = (const float*)d_in[1];   // [E, OUT, IN]
  const float* bias = (const float*)d_in[2];   // [E, OUT]
  const float* act  = (const float*)d_in[3];   // [B, E]
  int*   ws  = (int*)d_ws;
  float* out = (float*)d_out;

  hipLaunchKernelGGL(k_zero,  dim3(1),          dim3(64),      0, stream, ws);
  hipLaunchKernelGGL(k_topk,  dim3(B_N / 256),  dim3(256),     0, stream, act, ws);
  hipLaunchKernelGGL(k_tiles, dim3(1),          dim3(64),      0, stream, ws);
  hipLaunchKernelGGL(k_gemm,  dim3(GRID_GEMM),  dim3(THREADS), 0, stream,
                     feat, Wm, bias, ws, out);
}

// Round 3
// 147.794 us; speedup vs baseline: 1.8277x; 1.8277x over previous
//
#include <hip/hip_runtime.h>
#include <hip/hip_bf16.h>
#include <stdint.h>

// Problem constants (from reference)
#define B_N     2048
#define E_N     32
#define IN_N    2048
#define OUT_N   1024
#define TOPK    4

// GEMM tiling
#define BM      128
#define BN      256
#define BK      32
#define NT      (OUT_N / BN)        // 4 n-tiles
#define NKT     (IN_N / BK)         // 64 k-steps
#define THREADS 512                 // 8 waves, 2m x 4n, wave tile 64x64
#define MAX_SLOTS 96                // sum ceil(c_e/128) <= 8192/128 + 31 = 95
#define GRID_GEMM (MAX_SLOTS * NT)  // 384, %8==0 (XCD swizzle bijective)

// ws layout (int words)
#define WS_COUNTS 0     // [32]
#define WS_NSLOTS 32    // [1]
#define WS_DESC   64    // [MAX_SLOTS]  packed (e<<6)|mt
#define WS_LISTS  256   // [E_N][B_N]   packed (b<<2)|k

typedef float  f32x4  __attribute__((ext_vector_type(4)));
typedef __bf16 bf16x8 __attribute__((ext_vector_type(8)));

union Pack8 { bf16x8 v; uint4 u; };

__device__ __forceinline__ uint4 pack8(f32x4 lo, f32x4 hi) {
  Pack8 p;
#pragma unroll
  for (int j = 0; j < 4; ++j) { p.v[j] = (__bf16)lo[j]; p.v[j + 4] = (__bf16)hi[j]; }
  return p.u;
}
__device__ __forceinline__ bf16x8 as_frag(uint4 u) { Pack8 p; p.u = u; return p.v; }

// ---------------- kernel 0: zero counters ----------------
__global__ void k_zero(int* __restrict__ ws) {
  if (threadIdx.x < 64) ws[threadIdx.x] = 0;
}

// ---------------- kernel 1: top-4-smallest + bucket ----------------
__global__ void k_topk(const float* __restrict__ act, int* __restrict__ ws) {
  int b = blockIdx.x * blockDim.x + threadIdx.x;
  if (b >= B_N) return;
  float v[E_N];
  const float* a = act + (size_t)b * E_N;
#pragma unroll
  for (int e = 0; e < E_N; ++e) v[e] = a[e];
  unsigned chosen = 0;
#pragma unroll
  for (int k = 0; k < TOPK; ++k) {
    float mv = 3.4e38f; int mi = 0;
#pragma unroll
    for (int e = 0; e < E_N; ++e) {
      bool sel = (((chosen >> e) & 1u) == 0u) && (v[e] < mv);  // strict <: stable (first index)
      mv = sel ? v[e] : mv;
      mi = sel ? e : mi;
    }
    chosen |= (1u << mi);
    int pos = atomicAdd(&ws[WS_COUNTS + mi], 1);
    ws[WS_LISTS + mi * B_N + pos] = (b << 2) | k;
  }
}

// ---------------- kernel 2: build tile worklist ----------------
__global__ void k_tiles(int* __restrict__ ws) {
  int e = threadIdx.x;  // launched with 64 (one wave)
  int c = (e < E_N) ? ws[WS_COUNTS + e] : 0;
  int t = (c + BM - 1) / BM;
  int off = 0, tot = 0;
  for (int j = 0; j < E_N; ++j) {
    int tj = __shfl(t, j, 64);
    if (j < e) off += tj;
    tot += tj;
  }
  if (e < E_N) {
    for (int i = 0; i < t; ++i) ws[WS_DESC + off + i] = (e << 6) | i;
  }
  if (e == 0) ws[WS_NSLOTS] = tot;
}

// ---------------- kernel 3: grouped GEMM (bf16 MFMA) ----------------
// 128x256 block tile, BK=32, reg prefetch + LDS dbuf, 1 barrier/K-step.
// 8 waves in 2m x 4n grid; wave tile 64x64 (4x4 fragments).
// nt-major work order: blocks sharing a W slice (same e,nt; diff mt) are
// adjacent -> co-resident on one XCD -> L2 reuse of W.
__global__ __launch_bounds__(THREADS, 2)
void k_gemm(const float* __restrict__ feat, const float* __restrict__ Wm,
            const float* __restrict__ bias, const int* __restrict__ ws,
            float* __restrict__ out) {
  // XCD-chunked swizzle (bijective: GRID_GEMM % 8 == 0); chunk = 48 blocks
  int p = blockIdx.x;
  int L = (p & 7) * (GRID_GEMM / 8) + (p >> 3);
  int nt   = L / MAX_SLOTS;   // nt-major
  int slot = L % MAX_SLOTS;
  if (slot >= ws[WS_NSLOTS]) return;
  int desc = ws[WS_DESC + slot];
  int e = desc >> 6, mt = desc & 63;
  int count = ws[WS_COUNTS + e];
  int m0 = mt * BM;

  // LDS per buffer: A 512 + W 1024 uint4 slots (24KB); dbuf = 48KB
  __shared__ uint4 lds4[3072];
  __shared__ int gids[BM];

  int tid  = threadIdx.x;
  int lane = tid & 63;
  int wv   = tid >> 6;
  int wm   = wv >> 2;   // 0..1
  int wn   = wv & 3;    // 0..3

  // --- A staging: 1 slot/thread (8 f32 -> 8 bf16 = 16B) ---
  int arow = tid >> 2, kq = tid & 3;
  int gid = -1;
  if (m0 + arow < count) gid = ws[WS_LISTS + e * B_N + m0 + arow];
  if (kq == 0) gids[arow] = gid;
  const float* aptr = feat + (size_t)(gid >> 2) * IN_N + kq * 8;  // deref'd only if gid>=0
  int a_wi = arow * 4 + (kq ^ ((arow >> 1) & 3));

  // --- W staging: 2 slots/thread (rows t>>2 and t>>2+128) ---
  int wrow = tid >> 2;
  const float* wptr = Wm + ((size_t)e * OUT_N + (size_t)(nt * BN + wrow)) * IN_N + kq * 8;
  int w_wi0 = 512 + wrow * 4 + (kq ^ ((wrow >> 1) & 3));
  int w_wi1 = w_wi0 + 512;   // row+128: same swizzle bits, +128 rows * 4 slots

  // --- fragment read indices (uint4 units, swizzled) ---
  int aidx[4], bidx[4];
#pragma unroll
  for (int mi = 0; mi < 4; ++mi) {
    int r = wm * 64 + mi * 16 + (lane & 15);
    aidx[mi] = r * 4 + ((lane >> 4) ^ ((r >> 1) & 3));
  }
#pragma unroll
  for (int ni = 0; ni < 4; ++ni) {
    int r = wn * 64 + ni * 16 + (lane & 15);
    bidx[ni] = 512 + r * 4 + ((lane >> 4) ^ ((r >> 1) & 3));
  }

  f32x4 ra[2], rw[4];
  const f32x4 zero4 = {0.f, 0.f, 0.f, 0.f};

#define LOAD_TILE(K0)                                                        \
  do {                                                                       \
    if (gid >= 0) {                                                          \
      ra[0] = *(const f32x4*)(aptr + (K0));                                  \
      ra[1] = *(const f32x4*)(aptr + (K0) + 4);                              \
    } else { ra[0] = zero4; ra[1] = zero4; }                                 \
    rw[0] = *(const f32x4*)(wptr + (K0));                                    \
    rw[1] = *(const f32x4*)(wptr + (K0) + 4);                                \
    rw[2] = *(const f32x4*)(wptr + (size_t)128 * IN_N + (K0));               \
    rw[3] = *(const f32x4*)(wptr + (size_t)128 * IN_N + (K0) + 4);           \
  } while (0)

#define WRITE_TILE(BUF)                                                      \
  do {                                                                       \
    lds4[(BUF) * 1536 + a_wi]  = pack8(ra[0], ra[1]);                        \
    lds4[(BUF) * 1536 + w_wi0] = pack8(rw[0], rw[1]);                        \
    lds4[(BUF) * 1536 + w_wi1] = pack8(rw[2], rw[3]);                        \
  } while (0)

  f32x4 acc[4][4] = {};  // [mi][ni]

  LOAD_TILE(0);
  WRITE_TILE(0);
  __syncthreads();

  int cur = 0;
#pragma unroll 1
  for (int kt = 0; kt < NKT; ++kt) {
    bool pf = (kt + 1 < NKT);
    if (pf) LOAD_TILE((kt + 1) * BK);   // issue next tile's loads first

    int base = cur * 1536;
    bf16x8 af[4], bfr[4];
#pragma unroll
    for (int mi = 0; mi < 4; ++mi) af[mi] = as_frag(lds4[base + aidx[mi]]);
#pragma unroll
    for (int ni = 0; ni < 4; ++ni) bfr[ni] = as_frag(lds4[base + bidx[ni]]);
#pragma unroll
    for (int mi = 0; mi < 4; ++mi)
#pragma unroll
      for (int ni = 0; ni < 4; ++ni)
        acc[mi][ni] = __builtin_amdgcn_mfma_f32_16x16x32_bf16(af[mi], bfr[ni], acc[mi][ni], 0, 0, 0);

    if (pf) WRITE_TILE(cur ^ 1);        // other buffer
    __syncthreads();                    // writes landed + all done reading cur
    cur ^= 1;
  }

  // --- epilogue: D row=(lane>>4)*4+j, col=lane&15 ---
  int grr[16];
#pragma unroll
  for (int mi = 0; mi < 4; ++mi)
#pragma unroll
    for (int j = 0; j < 4; ++j)
      grr[mi * 4 + j] = gids[wm * 64 + mi * 16 + (lane >> 4) * 4 + j];

#pragma unroll
  for (int ni = 0; ni < 4; ++ni) {
    int col = nt * BN + wn * 64 + ni * 16 + (lane & 15);
    float bs = bias[e * OUT_N + col];
#pragma unroll
    for (int mi = 0; mi < 4; ++mi) {
#pragma unroll
      for (int j = 0; j < 4; ++j) {
        int g = grr[mi * 4 + j];
        if (g >= 0) out[(size_t)g * OUT_N + col] = acc[mi][ni][j] + bs;
      }
    }
  }
}

extern "C" void kernel_launch(void* const* d_in, const int* in_sizes, int n_in,
                              void* d_out, int out_size, void* d_ws, size_t ws_size,
                              hipStream_t stream) {
  const float* feat = (const float*)d_in[0];   // [B, IN]
  const float* Wm   = (const float*)d_in[1];   // [E, OUT, IN]
  const float* bias = (const float*)d_in[2];   // [E, OUT]
  const float* act  = (const float*)d_in[3];   // [B, E]
  int*   ws  = (int*)d_ws;
  float* out = (float*)d_out;

  hipLaunchKernelGGL(k_zero,  dim3(1),          dim3(64),      0, stream, ws);
  hipLaunchKernelGGL(k_topk,  dim3(B_N / 256),  dim3(256),     0, stream, act, ws);
  hipLaunchKernelGGL(k_tiles, dim3(1),          dim3(64),      0, stream, ws);
  hipLaunchKernelGGL(k_gemm,  dim3(GRID_GEMM),  dim3(THREADS), 0, stream,
                     feat, Wm, bias, ws, out);
}